// Round 1
// baseline (5784.044 us; speedup 1.0000x reference)
//
#include <hip/hip_runtime.h>
#include <hip/hip_bf16.h>
#include <math.h>

#define NPTS 4096
#define DIM  256
#define MAX_ITERS 10
#define EPSN 1e-8f
#define BM 64
#define KC 32
#define ASPL 8   // splits for NMS kernels (fixed)

// ---------------- prep: xhat = normalize(x), c = x, reset flags/counters ----------------
__global__ void prepK(const float* __restrict__ x, float* __restrict__ xhat,
                      float* __restrict__ c, int* done, int* shiftbits,
                      int* counts, int* keep)
{
    int row = blockIdx.x, t = threadIdx.x;
    float v = x[(size_t)row*DIM + t];
    __shared__ float red[256];
    red[t] = v*v;
    __syncthreads();
    for (int s = 128; s > 0; s >>= 1) { if (t < s) red[t] += red[t+s]; __syncthreads(); }
    float rn = 1.0f / fmaxf(sqrtf(red[0]), EPSN);
    xhat[(size_t)row*DIM + t] = v*rn;
    c[(size_t)row*DIM + t]    = v;
    int i = row*256 + t;
    if (i < NPTS) { counts[i] = 0; keep[i] = 0; }
    if (row == 0 && t == 0) { *done = 0; *shiftbits = 0; }
}

// ---------------- fused mean-shift iteration (one split of the K range) ----------------
struct StageAB { float A[KC][68]; float B[KC][68]; };
union Stage { StageAB ab; float XC[16][260]; };

__global__ __launch_bounds__(256) void fusedK(
    const float* __restrict__ x, const float* __restrict__ xhat,
    float* __restrict__ c, const float* __restrict__ cnew,
    float* __restrict__ part, float* __restrict__ psum,
    const int* __restrict__ done, const float* __restrict__ sigma,
    int it, int splits)
{
    if (*done) return;
    const int I  = blockIdx.x * BM;
    const int bs = blockIdx.y;
    const int JL = NPTS / splits;
    const int J0 = bs * JL;
    const int tid = threadIdx.x;
    const int tx = tid & 15, ty = tid >> 4;

    __shared__ float Ws[BM][68];
    __shared__ Stage st;
    __shared__ float rn[BM];
    __shared__ float red4[BM][4];

    // commit previous iteration's accepted update (identical values written by
    // all split-blocks sharing this row tile -> benign)
    if (it > 0) {
        const float4* src = (const float4*)(cnew + (size_t)I*DIM);
        float4*       dst = (float4*)(c + (size_t)I*DIM);
        for (int k = tid; k < BM*DIM/4; k += 256) dst[k] = src[k];
    }
    __syncthreads();

    // row norms of c[I..I+BM)
    {
        int r = tid >> 2, q = tid & 3;
        const float* p = c + (size_t)(I + r)*DIM + q*64;
        float ss = 0.f;
        #pragma unroll
        for (int k = 0; k < 64; k += 4) {
            float4 v = *(const float4*)(p + k);
            ss = fmaf(v.x,v.x, fmaf(v.y,v.y, fmaf(v.z,v.z, fmaf(v.w,v.w, ss))));
        }
        red4[r][q] = ss;
    }
    __syncthreads();
    if (tid < BM) {
        float ss = red4[tid][0]+red4[tid][1]+red4[tid][2]+red4[tid][3];
        rn[tid] = 1.0f / fmaxf(sqrtf(ss), EPSN);
    }
    __syncthreads();

    const float sg = *sigma;
    const float ig = 1.0f / (2.0f * sg * sg);

    float acc[4][16];
    #pragma unroll
    for (int a=0;a<4;a++){
        #pragma unroll
        for (int b2=0;b2<16;b2++) acc[a][b2]=0.f;
    }
    float rs[4] = {0.f,0.f,0.f,0.f};

    const int NT = JL / 64;
    for (int jt = 0; jt < NT; ++jt) {
        const int J = J0 + jt*64;
        float s[4][4];
        #pragma unroll
        for (int a=0;a<4;a++){
            #pragma unroll
            for (int b2=0;b2<4;b2++) s[a][b2]=0.f;
        }

        // ---- phase A: S(64x64) = Chat_I . Xhat_J^T ----
        for (int kc = 0; kc < DIM; kc += KC) {
            {
                int i = tid >> 2, q = tid & 3;
                float r = rn[i];
                const float* pA = c + (size_t)(I+i)*DIM + kc + q*4;
                float4 a0 = *(const float4*)pA;
                float4 a1 = *(const float4*)(pA + 16);
                st.ab.A[q*4+0][i]  = a0.x*r;
                st.ab.A[q*4+1][i]  = a0.y*r;
                st.ab.A[q*4+2][i]  = a0.z*r;
                st.ab.A[q*4+3][i]  = a0.w*r;
                st.ab.A[q*4+16][i] = a1.x*r;
                st.ab.A[q*4+17][i] = a1.y*r;
                st.ab.A[q*4+18][i] = a1.z*r;
                st.ab.A[q*4+19][i] = a1.w*r;
                const float* pB = xhat + (size_t)(J+i)*DIM + kc + q*4;
                float4 b0 = *(const float4*)pB;
                float4 b1 = *(const float4*)(pB + 16);
                st.ab.B[q*4+0][i]  = b0.x;
                st.ab.B[q*4+1][i]  = b0.y;
                st.ab.B[q*4+2][i]  = b0.z;
                st.ab.B[q*4+3][i]  = b0.w;
                st.ab.B[q*4+16][i] = b1.x;
                st.ab.B[q*4+17][i] = b1.y;
                st.ab.B[q*4+18][i] = b1.z;
                st.ab.B[q*4+19][i] = b1.w;
            }
            __syncthreads();
            #pragma unroll
            for (int k = 0; k < KC; ++k) {
                float av[4], bv[4];
                *(float4*)av = *(const float4*)&st.ab.A[k][ty*4];
                *(float4*)bv = *(const float4*)&st.ab.B[k][tx*4];
                #pragma unroll
                for (int a=0;a<4;a++){
                    #pragma unroll
                    for (int b2=0;b2<4;b2++)
                        s[a][b2] = fmaf(av[a], bv[b2], s[a][b2]);
                }
            }
            __syncthreads();
        }

        // ---- weights ----
        #pragma unroll
        for (int a=0;a<4;a++){
            #pragma unroll
            for (int b2=0;b2<4;b2++){
                float w = expf((2.0f*(s[a][b2]-1.0f))*ig);
                Ws[ty*4+a][tx*4+b2] = w;
                rs[a] += w;
            }
        }
        __syncthreads();

        // ---- phase B: acc += W(64x64) . X_J(64x256) ----
        for (int jc = 0; jc < 64; jc += 16) {
            {
                int jj = tid >> 4, q = tid & 15;
                const float4* px = (const float4*)(x + (size_t)(J+jc+jj)*DIM) + q*4;
                float4* pl = (float4*)&st.XC[jj][q*16];
                pl[0]=px[0]; pl[1]=px[1]; pl[2]=px[2]; pl[3]=px[3];
            }
            __syncthreads();
            #pragma unroll
            for (int jj = 0; jj < 16; ++jj) {
                float wv[4];
                #pragma unroll
                for (int a=0;a<4;a++) wv[a] = Ws[ty*4+a][jc+jj];
                #pragma unroll
                for (int c4=0;c4<4;c4++){
                    float xv[4];
                    *(float4*)xv = *(const float4*)&st.XC[jj][tx*4 + 64*c4];
                    #pragma unroll
                    for (int a=0;a<4;a++){
                        #pragma unroll
                        for (int cc=0;cc<4;cc++)
                            acc[a][c4*4+cc] = fmaf(wv[a], xv[cc], acc[a][c4*4+cc]);
                    }
                }
            }
            __syncthreads();
        }
    }

    // write partial weighted sums
    float* pp = part + ((size_t)bs*NPTS + I)*DIM;
    #pragma unroll
    for (int a=0;a<4;a++){
        int row = ty*4+a;
        #pragma unroll
        for (int c4=0;c4<4;c4++){
            float4 v = make_float4(acc[a][c4*4+0], acc[a][c4*4+1],
                                   acc[a][c4*4+2], acc[a][c4*4+3]);
            *(float4*)(pp + (size_t)row*DIM + tx*4 + 64*c4) = v;
        }
    }
    // row-sum reduce across tx (reuse Ws)
    __syncthreads();
    #pragma unroll
    for (int a=0;a<4;a++) Ws[ty*4+a][tx] = rs[a];
    __syncthreads();
    if (tid < BM) {
        float v = 0.f;
        #pragma unroll
        for (int k=0;k<16;k++) v += Ws[tid][k];
        psum[(size_t)bs*NPTS + I + tid] = v;
    }
}

// ---------------- reduce partials -> cnew, shift max ----------------
__global__ void reduceK(const float* __restrict__ part, const float* __restrict__ psum,
                        const float* __restrict__ c, float* __restrict__ cnew,
                        const int* __restrict__ done, int* shiftbits, int splits)
{
    if (*done) return;
    int row = blockIdx.x, t = threadIdx.x;
    float s = 0.f;
    for (int sp = 0; sp < splits; ++sp)
        s += part[((size_t)sp*NPTS + row)*DIM + t];
    float rsum = 0.f;
    for (int sp = 0; sp < splits; ++sp)
        rsum += psum[(size_t)sp*NPTS + row];
    float cn = s / rsum;
    cnew[(size_t)row*DIM + t] = cn;
    float d = cn - c[(size_t)row*DIM + t];
    __shared__ float red[256];
    red[t] = d*d;
    __syncthreads();
    for (int st2 = 128; st2 > 0; st2 >>= 1) { if (t < st2) red[t] += red[t+st2]; __syncthreads(); }
    if (t == 0) atomicMax(shiftbits, __float_as_int(sqrtf(red[0])));
}

__global__ void flagK(int* done, int* shiftbits)
{
    float sh = __int_as_float(*shiftbits);
    if (!*done && sh < 1e-5f) *done = 1;
    *shiftbits = 0;
}

__global__ void finalK(const int* __restrict__ done, const float* __restrict__ c,
                       const float* __restrict__ cnew, float* __restrict__ out)
{
    int i = blockIdx.x*256 + threadIdx.x;
    out[i] = (*done) ? c[i] : cnew[i];
}

__global__ void normcK(const float* __restrict__ cen, float* __restrict__ chat)
{
    int row = blockIdx.x, t = threadIdx.x;
    float v = cen[(size_t)row*DIM + t];
    __shared__ float red[256];
    red[t] = v*v;
    __syncthreads();
    for (int s = 128; s > 0; s >>= 1) { if (t < s) red[t] += red[t+s]; __syncthreads(); }
    float rn = 1.0f / fmaxf(sqrtf(red[0]), EPSN);
    chat[(size_t)row*DIM + t] = v*rn;
}

// ---------------- NMS: per-point argmin over centroids (split) ----------------
__global__ __launch_bounds__(256) void argminK(
    const float* __restrict__ chat, const float* __restrict__ xhat,
    float* __restrict__ aval, int* __restrict__ aidx)
{
    const int P  = blockIdx.x * 64;
    const int ms = blockIdx.y;
    const int M0 = ms * (NPTS/ASPL);
    const int tid = threadIdx.x;
    const int tx = tid & 15, ty = tid >> 4;

    __shared__ float A[KC][68];
    __shared__ float B[KC][68];
    __shared__ float mv[16][65];
    __shared__ int   mi[16][65];

    float bv[4] = {3.4e38f,3.4e38f,3.4e38f,3.4e38f};
    int   bm[4] = {0,0,0,0};

    for (int mt = 0; mt < (NPTS/ASPL)/64; ++mt) {
        const int M = M0 + mt*64;
        float s[4][4];
        #pragma unroll
        for (int a=0;a<4;a++){
            #pragma unroll
            for (int b2=0;b2<4;b2++) s[a][b2]=0.f;
        }
        for (int kc = 0; kc < DIM; kc += KC) {
            {
                int i = tid >> 2, q = tid & 3;
                const float* pA = chat + (size_t)(M+i)*DIM + kc + q*4;
                float4 a0 = *(const float4*)pA;
                float4 a1 = *(const float4*)(pA + 16);
                A[q*4+0][i]=a0.x; A[q*4+1][i]=a0.y; A[q*4+2][i]=a0.z; A[q*4+3][i]=a0.w;
                A[q*4+16][i]=a1.x; A[q*4+17][i]=a1.y; A[q*4+18][i]=a1.z; A[q*4+19][i]=a1.w;
                const float* pB = xhat + (size_t)(P+i)*DIM + kc + q*4;
                float4 b0 = *(const float4*)pB;
                float4 b1 = *(const float4*)(pB + 16);
                B[q*4+0][i]=b0.x; B[q*4+1][i]=b0.y; B[q*4+2][i]=b0.z; B[q*4+3][i]=b0.w;
                B[q*4+16][i]=b1.x; B[q*4+17][i]=b1.y; B[q*4+18][i]=b1.z; B[q*4+19][i]=b1.w;
            }
            __syncthreads();
            #pragma unroll
            for (int k = 0; k < KC; ++k) {
                float av[4], bb[4];
                *(float4*)av = *(const float4*)&A[k][ty*4];
                *(float4*)bb = *(const float4*)&B[k][tx*4];
                #pragma unroll
                for (int a=0;a<4;a++){
                    #pragma unroll
                    for (int b2=0;b2<4;b2++)
                        s[a][b2] = fmaf(av[a], bb[b2], s[a][b2]);
                }
            }
            __syncthreads();
        }
        #pragma unroll
        for (int b2=0;b2<4;b2++){
            #pragma unroll
            for (int a=0;a<4;a++){
                float d = 2.0f*(1.0f - s[a][b2]);
                int m = M + ty*4 + a;
                if (d < bv[b2]) { bv[b2]=d; bm[b2]=m; }   // ascending m scan: strict < keeps first
            }
        }
    }
    #pragma unroll
    for (int b2=0;b2<4;b2++){ mv[ty][tx*4+b2] = bv[b2]; mi[ty][tx*4+b2] = bm[b2]; }
    __syncthreads();
    if (tid < 64) {
        float v = mv[0][tid]; int m = mi[0][tid];
        for (int k=1;k<16;k++){
            float v2 = mv[k][tid]; int m2 = mi[k][tid];
            if (v2 < v || (v2 == v && m2 < m)) { v=v2; m=m2; }
        }
        aval[(size_t)ms*NPTS + P + tid] = v;
        aidx[(size_t)ms*NPTS + P + tid] = m;
    }
}

__global__ void acombineK(const float* __restrict__ aval, const int* __restrict__ aidx,
                          int* __restrict__ counts)
{
    int p = blockIdx.x*256 + threadIdx.x;
    float bv = 3.4e38f; int bm = 1<<30;
    for (int s = 0; s < ASPL; ++s) {
        float v = aval[(size_t)s*NPTS + p]; int m = aidx[(size_t)s*NPTS + p];
        if (v < bv || (v == bv && m < bm)) { bv=v; bm=m; }
    }
    atomicAdd(&counts[bm], 1);
}

// ---------------- NMS: per-centroid argmax of close*counts (split) ----------------
__global__ __launch_bounds__(256) void ccK(
    const float* __restrict__ chat, const int* __restrict__ counts,
    const float* __restrict__ sigma,
    float* __restrict__ cval, int* __restrict__ cidx)
{
    const int Mrow = blockIdx.x * 64;
    const int js   = blockIdx.y;
    const int J0   = js * (NPTS/ASPL);
    const float bw = *sigma;
    const int tid = threadIdx.x;
    const int tx = tid & 15, ty = tid >> 4;

    __shared__ float A[KC][68];
    __shared__ float B[KC][68];
    __shared__ float cnt[64];
    __shared__ float mv[64][17];
    __shared__ int   mi[64][17];

    float bvv[4] = {-1.f,-1.f,-1.f,-1.f};
    int   bjj[4] = {1<<30,1<<30,1<<30,1<<30};

    for (int jt = 0; jt < (NPTS/ASPL)/64; ++jt) {
        const int J = J0 + jt*64;
        if (tid < 64) cnt[tid] = (float)counts[J + tid];
        float s[4][4];
        #pragma unroll
        for (int a=0;a<4;a++){
            #pragma unroll
            for (int b2=0;b2<4;b2++) s[a][b2]=0.f;
        }
        for (int kc = 0; kc < DIM; kc += KC) {
            {
                int i = tid >> 2, q = tid & 3;
                const float* pA = chat + (size_t)(Mrow+i)*DIM + kc + q*4;
                float4 a0 = *(const float4*)pA;
                float4 a1 = *(const float4*)(pA + 16);
                A[q*4+0][i]=a0.x; A[q*4+1][i]=a0.y; A[q*4+2][i]=a0.z; A[q*4+3][i]=a0.w;
                A[q*4+16][i]=a1.x; A[q*4+17][i]=a1.y; A[q*4+18][i]=a1.z; A[q*4+19][i]=a1.w;
                const float* pB = chat + (size_t)(J+i)*DIM + kc + q*4;
                float4 b0 = *(const float4*)pB;
                float4 b1 = *(const float4*)(pB + 16);
                B[q*4+0][i]=b0.x; B[q*4+1][i]=b0.y; B[q*4+2][i]=b0.z; B[q*4+3][i]=b0.w;
                B[q*4+16][i]=b1.x; B[q*4+17][i]=b1.y; B[q*4+18][i]=b1.z; B[q*4+19][i]=b1.w;
            }
            __syncthreads();
            #pragma unroll
            for (int k = 0; k < KC; ++k) {
                float av[4], bb[4];
                *(float4*)av = *(const float4*)&A[k][ty*4];
                *(float4*)bb = *(const float4*)&B[k][tx*4];
                #pragma unroll
                for (int a=0;a<4;a++){
                    #pragma unroll
                    for (int b2=0;b2<4;b2++)
                        s[a][b2] = fmaf(av[a], bb[b2], s[a][b2]);
                }
            }
            __syncthreads();
        }
        #pragma unroll
        for (int a=0;a<4;a++){
            #pragma unroll
            for (int b2=0;b2<4;b2++){
                float d = 2.0f*(1.0f - s[a][b2]);
                float val = (d < bw) ? cnt[tx*4+b2] : 0.0f;
                int j = J + tx*4 + b2;
                if (val > bvv[a] || (val == bvv[a] && j < bjj[a])) { bvv[a]=val; bjj[a]=j; }
            }
        }
        __syncthreads();  // protect cnt/A/B before next tile's writes
    }
    #pragma unroll
    for (int a=0;a<4;a++){ mv[ty*4+a][tx] = bvv[a]; mi[ty*4+a][tx] = bjj[a]; }
    __syncthreads();
    if (tid < 64) {
        float v = mv[tid][0]; int j = mi[tid][0];
        for (int k=1;k<16;k++){
            float v2 = mv[tid][k]; int j2 = mi[tid][k];
            if (v2 > v || (v2 == v && j2 < j)) { v=v2; j=j2; }
        }
        cval[(size_t)js*NPTS + Mrow + tid] = v;
        cidx[(size_t)js*NPTS + Mrow + tid] = j;
    }
}

__global__ void ccombineK(const float* __restrict__ cval, const int* __restrict__ cidx,
                          const int* __restrict__ counts, int* __restrict__ keep)
{
    int m = blockIdx.x*256 + threadIdx.x;
    float bv = -1.0f; int bj = 1<<30;
    for (int s = 0; s < ASPL; ++s) {
        float v = cval[(size_t)s*NPTS + m]; int j = cidx[(size_t)s*NPTS + m];
        if (v > bv || (v == bv && j < bj)) { bv=v; bj=j; }
    }
    if (counts[m] > 0) atomicOr(&keep[bj], 1);
}

__global__ void keepwriteK(const int* __restrict__ keep, float* __restrict__ out)
{
    int i = blockIdx.x*256 + threadIdx.x;
    out[(size_t)NPTS*DIM + i] = keep[i] ? 1.0f : 0.0f;
}

// ---------------- host ----------------
extern "C" void kernel_launch(void* const* d_in, const int* in_sizes, int n_in,
                              void* d_out, int out_size, void* d_ws, size_t ws_size,
                              hipStream_t stream)
{
    const float* x     = (const float*)d_in[0];
    const float* sigma = (const float*)d_in[1];
    float* out = (float*)d_out;

    const size_t ND = (size_t)NPTS * DIM;
    size_t o_xhat, o_c, o_cnew, o_part, o_psum, o_aval, o_aidx, o_cval, o_cidx,
           o_counts, o_keep, o_done, o_shift;

    int splits = 8;
    for (;;) {
        size_t off = 0;
        auto take = [&](size_t nb) { size_t a = off; off += (nb + 255) & ~(size_t)255; return a; };
        o_xhat  = take(ND*4);
        o_c     = take(ND*4);
        o_cnew  = take(ND*4);
        o_part  = take((size_t)splits*ND*4);
        o_psum  = take((size_t)splits*NPTS*4);
        o_aval  = take((size_t)ASPL*NPTS*4);
        o_aidx  = take((size_t)ASPL*NPTS*4);
        o_cval  = take((size_t)ASPL*NPTS*4);
        o_cidx  = take((size_t)ASPL*NPTS*4);
        o_counts= take((size_t)NPTS*4);
        o_keep  = take((size_t)NPTS*4);
        o_done  = take(256);
        o_shift = take(256);
        if (off <= ws_size || splits == 1) break;
        splits >>= 1;
    }

    char* W = (char*)d_ws;
    float* xhat = (float*)(W + o_xhat);
    float* c    = (float*)(W + o_c);
    float* cnew = (float*)(W + o_cnew);
    float* part = (float*)(W + o_part);
    float* psum = (float*)(W + o_psum);
    float* chat = part;                 // alias: part unused during NMS
    float* aval = (float*)(W + o_aval);
    int*   aidx = (int*)  (W + o_aidx);
    float* cval = (float*)(W + o_cval);
    int*   cidx = (int*)  (W + o_cidx);
    int*   counts = (int*)(W + o_counts);
    int*   keep   = (int*)(W + o_keep);
    int*   done   = (int*)(W + o_done);
    int*   shiftb = (int*)(W + o_shift);

    prepK<<<dim3(NPTS), dim3(256), 0, stream>>>(x, xhat, c, done, shiftb, counts, keep);

    for (int it = 0; it < MAX_ITERS; ++it) {
        fusedK<<<dim3(NPTS/BM, splits), dim3(256), 0, stream>>>(
            x, xhat, c, cnew, part, psum, done, sigma, it, splits);
        reduceK<<<dim3(NPTS), dim3(256), 0, stream>>>(
            part, psum, c, cnew, done, shiftb, splits);
        flagK<<<dim3(1), dim3(1), 0, stream>>>(done, shiftb);
    }

    finalK<<<dim3(NPTS), dim3(256), 0, stream>>>(done, c, cnew, out);
    normcK<<<dim3(NPTS), dim3(256), 0, stream>>>(out, chat);

    argminK<<<dim3(NPTS/64, ASPL), dim3(256), 0, stream>>>(chat, xhat, aval, aidx);
    acombineK<<<dim3(NPTS/256), dim3(256), 0, stream>>>(aval, aidx, counts);
    ccK<<<dim3(NPTS/64, ASPL), dim3(256), 0, stream>>>(chat, counts, sigma, cval, cidx);
    ccombineK<<<dim3(NPTS/256), dim3(256), 0, stream>>>(cval, cidx, counts, keep);
    keepwriteK<<<dim3(NPTS/256), dim3(256), 0, stream>>>(keep, out);
}

// Round 2
// 2250.326 us; speedup vs baseline: 2.5703x; 2.5703x over previous
//
#include <hip/hip_runtime.h>
#include <math.h>

#define NPTS 4096
#define DIM  256
#define MAX_ITERS 10
#define EPSN 1e-8f
#define ASPL 8

typedef __bf16 bf16x8 __attribute__((ext_vector_type(8)));
typedef float  f32x4  __attribute__((ext_vector_type(4)));
typedef unsigned short u16x8 __attribute__((ext_vector_type(8)));
typedef unsigned short u16x4 __attribute__((ext_vector_type(4)));
typedef unsigned short U16;

__device__ __forceinline__ U16 bf16_rne(float f) {
    unsigned int u = __float_as_uint(f);
    u += 0x7FFFu + ((u >> 16) & 1u);
    return (U16)(u >> 16);
}

__device__ __forceinline__ void glds16(const void* g, void* l) {
    __builtin_amdgcn_global_load_lds(
        (const __attribute__((address_space(1))) unsigned int*)g,
        (__attribute__((address_space(3))) unsigned int*)l,
        16, 0, 0);
}

// ---------------- prep ----------------
__global__ void initK(int* counts, int* keep, int* done, int* shiftb) {
    int i = blockIdx.x * 256 + threadIdx.x;
    if (i < NPTS) { counts[i] = 0; keep[i] = 0; }
    if (i == 0) { *done = 0; *shiftb = 0; }
}

// x -> c (copy), xhat_f32, xhat hi/lo splits
__global__ void normxK(const float* __restrict__ x, float* __restrict__ c,
                       float* __restrict__ xf, U16* __restrict__ xh, U16* __restrict__ xl) {
    int m = blockIdx.x, t = threadIdx.x;
    float v = x[(size_t)m*DIM + t];
    __shared__ float red[256];
    red[t] = v*v; __syncthreads();
    for (int s = 128; s > 0; s >>= 1) { if (t < s) red[t] += red[t+s]; __syncthreads(); }
    float rn = 1.0f / fmaxf(sqrtf(red[0]), EPSN);
    float hv = v*rn;
    U16 hb = bf16_rne(hv);
    float hf = __uint_as_float((unsigned)hb << 16);
    U16 lb = bf16_rne(hv - hf);
    c [(size_t)m*DIM + t] = v;
    xf[(size_t)m*DIM + t] = hv;
    xh[(size_t)m*DIM + t] = hb;
    xl[(size_t)m*DIM + t] = lb;
}

// x^T split: Xt[d][p] = x[p][d] as bf16 hi/lo
__global__ void transpK(const float* __restrict__ x, U16* __restrict__ Xth, U16* __restrict__ Xtl) {
    int bm = blockIdx.x, bd = blockIdx.y;   // 128 x 8 grid of 32x32 tiles
    int t = threadIdx.x;
    __shared__ float sh[32][33];
    int r = t >> 3, cq = (t & 7) * 4;
    float4 v = *(const float4*)&x[(size_t)(bm*32 + r)*DIM + bd*32 + cq];
    sh[r][cq] = v.x; sh[r][cq+1] = v.y; sh[r][cq+2] = v.z; sh[r][cq+3] = v.w;
    __syncthreads();
    int dd = t >> 3, mq = (t & 7) * 4;
    u16x4 h4, l4;
    #pragma unroll
    for (int j = 0; j < 4; ++j) {
        float f = sh[mq + j][dd];
        U16 hb = bf16_rne(f);
        h4[j] = hb;
        l4[j] = bf16_rne(f - __uint_as_float((unsigned)hb << 16));
    }
    size_t off = (size_t)(bd*32 + dd)*NPTS + bm*32 + mq;
    *(u16x4*)&Xth[off] = h4;
    *(u16x4*)&Xtl[off] = l4;
}

// commit (optional) + normalize + split current centroids
__global__ void normsplitK(float* __restrict__ c, const float* __restrict__ cnew,
                           U16* __restrict__ chh, U16* __restrict__ chl,
                           const int* __restrict__ done, int commit) {
    if (*done) return;
    int m = blockIdx.x, t = threadIdx.x;
    float v;
    if (commit) { v = cnew[(size_t)m*DIM + t]; c[(size_t)m*DIM + t] = v; }
    else        { v = c[(size_t)m*DIM + t]; }
    __shared__ float red[256];
    red[t] = v*v; __syncthreads();
    for (int s = 128; s > 0; s >>= 1) { if (t < s) red[t] += red[t+s]; __syncthreads(); }
    float rn = 1.0f / fmaxf(sqrtf(red[0]), EPSN);
    float hv = v*rn;
    U16 hb = bf16_rne(hv);
    float hf = __uint_as_float((unsigned)hb << 16);
    U16 lb = bf16_rne(hv - hf);
    chh[(size_t)m*DIM + t] = hb;
    chl[(size_t)m*DIM + t] = lb;
}

// ---------------- simK: S = chat . xhat^T (split-bf16 MFMA), epilogue exp -> W hi/lo + psum ----------------
__global__ __launch_bounds__(256) void simK(
    const U16* __restrict__ Ahg, const U16* __restrict__ Alg,
    const U16* __restrict__ Bhg, const U16* __restrict__ Blg,
    U16* __restrict__ Wh, U16* __restrict__ Wl,
    float* __restrict__ psum, const int* __restrict__ done,
    const float* __restrict__ sigma, int ch, int CHJ)
{
    if (*done) return;
    const int tid = threadIdx.x;
    const int lane = tid & 63, wid = tid >> 6;
    const int wr = wid & 1, wc = wid >> 1;
    const int I  = blockIdx.y * 128;
    const int Jl = blockIdx.x * 128;
    const int Jg = ch * CHJ + Jl;

    __shared__ union {
        U16 st[4][4096];                 // Ah/Al/Bh/Bl fragment-slot tiles (8KB each)
        unsigned int bounce[128 * 65];   // epilogue store bounce
    } L;

    f32x4 acc[4][4];
    #pragma unroll
    for (int a = 0; a < 4; ++a)
        #pragma unroll
        for (int b = 0; b < 4; ++b) { f32x4 z = {0.f,0.f,0.f,0.f}; acc[a][b] = z; }

    const float ig = 1.0f / (2.0f * (*sigma) * (*sigma));

    for (int k0 = 0; k0 < DIM; k0 += 32) {
        __syncthreads();
        #pragma unroll
        for (int h = 0; h < 2; ++h) {
            const int sb   = wid * 128 + h * 64;
            const int slot = sb + lane;
            const int row  = slot & 127, kg = slot >> 7;
            const int col  = k0 + kg * 8;
            glds16(Ahg + (size_t)(I  + row)*DIM + col, &L.st[0][(size_t)sb * 8]);
            glds16(Alg + (size_t)(I  + row)*DIM + col, &L.st[1][(size_t)sb * 8]);
            glds16(Bhg + (size_t)(Jg + row)*DIM + col, &L.st[2][(size_t)sb * 8]);
            glds16(Blg + (size_t)(Jg + row)*DIM + col, &L.st[3][(size_t)sb * 8]);
        }
        __syncthreads();
        bf16x8 fah[4], fal[4], fbh[4], fbl[4];
        const int roff = (lane >> 4) * 128 + (lane & 15);
        #pragma unroll
        for (int f = 0; f < 4; ++f) {
            const int sA = roff + wr*64 + f*16;
            const int sB = roff + wc*64 + f*16;
            fah[f] = *(const bf16x8*)&L.st[0][(size_t)sA * 8];
            fal[f] = *(const bf16x8*)&L.st[1][(size_t)sA * 8];
            fbh[f] = *(const bf16x8*)&L.st[2][(size_t)sB * 8];
            fbl[f] = *(const bf16x8*)&L.st[3][(size_t)sB * 8];
        }
        #pragma unroll
        for (int a = 0; a < 4; ++a)
            #pragma unroll
            for (int b = 0; b < 4; ++b) {
                acc[a][b] = __builtin_amdgcn_mfma_f32_16x16x32_bf16(fah[a], fbh[b], acc[a][b], 0,0,0);
                acc[a][b] = __builtin_amdgcn_mfma_f32_16x16x32_bf16(fah[a], fbl[b], acc[a][b], 0,0,0);
                acc[a][b] = __builtin_amdgcn_mfma_f32_16x16x32_bf16(fal[a], fbh[b], acc[a][b], 0,0,0);
            }
    }

    // epilogue: w = exp(2(s-1)ig), split to bf16 hi/lo, row-sums
    float rsum[4][4];
    unsigned int pk[4][4][4];
    #pragma unroll
    for (int a = 0; a < 4; ++a)
        #pragma unroll
        for (int i = 0; i < 4; ++i) rsum[a][i] = 0.f;
    #pragma unroll
    for (int a = 0; a < 4; ++a)
        #pragma unroll
        for (int b = 0; b < 4; ++b)
            #pragma unroll
            for (int i = 0; i < 4; ++i) {
                float w = expf(2.0f * (acc[a][b][i] - 1.0f) * ig);
                U16 hb = bf16_rne(w);
                float hf = __uint_as_float((unsigned)hb << 16);
                U16 lb = bf16_rne(w - hf);
                pk[a][b][i] = ((unsigned)lb << 16) | (unsigned)hb;
                rsum[a][i] += w;
            }
    #pragma unroll
    for (int msk = 1; msk < 16; msk <<= 1)
        #pragma unroll
        for (int a = 0; a < 4; ++a)
            #pragma unroll
            for (int i = 0; i < 4; ++i)
                rsum[a][i] += __shfl_xor(rsum[a][i], msk, 64);
    if ((lane & 15) == 0) {
        int cb = (Jg >> 6) + wc;
        #pragma unroll
        for (int a = 0; a < 4; ++a)
            #pragma unroll
            for (int i = 0; i < 4; ++i)
                psum[(size_t)cb*NPTS + I + wr*64 + a*16 + (lane>>4)*4 + i] = rsum[a][i];
    }

    // LDS-bounce coalesced store of W tile (layout: tile[128][128] row-major, tileIdx = jb*32 + rb)
    const size_t tbase = ((size_t)blockIdx.x * 32 + blockIdx.y) * 16384;
    __syncthreads();
    #pragma unroll
    for (int q = 0; q < 2; ++q) {
        if (wc == q) {
            #pragma unroll
            for (int a = 0; a < 4; ++a)
                #pragma unroll
                for (int b = 0; b < 4; ++b)
                    #pragma unroll
                    for (int i = 0; i < 4; ++i) {
                        int row = wr*64 + a*16 + (lane>>4)*4 + i;
                        int col = b*16 + (lane & 15);
                        L.bounce[row*65 + col] = pk[a][b][i];
                    }
        }
        __syncthreads();
        {
            int row = tid >> 1, half = tid & 1;
            int cbase = half * 32;
            #pragma unroll
            for (int s = 0; s < 4; ++s) {
                unsigned int u[8];
                #pragma unroll
                for (int j = 0; j < 8; ++j) u[j] = L.bounce[row*65 + cbase + s*8 + j];
                u16x8 hh, ll;
                #pragma unroll
                for (int j = 0; j < 8; ++j) { hh[j] = (U16)(u[j] & 0xFFFFu); ll[j] = (U16)(u[j] >> 16); }
                size_t off = tbase + (size_t)row*128 + q*64 + cbase + s*8;
                *(u16x8*)&Wh[off] = hh;
                *(u16x8*)&Wl[off] = ll;
            }
        }
        __syncthreads();
    }
}

// ---------------- wxK: cnum[slice] (+)= W . X  (split-bf16 MFMA over K=j) ----------------
__global__ __launch_bounds__(256) void wxK(
    const U16* __restrict__ Wh, const U16* __restrict__ Wl,
    const U16* __restrict__ Xth, const U16* __restrict__ Xtl,
    float* __restrict__ cnum, const int* __restrict__ done,
    int ch, int CHJ, int klen, int first)
{
    if (*done) return;
    const int tid = threadIdx.x;
    const int lane = tid & 63, wid = tid >> 6;
    const int wr = wid & 1, wc = wid >> 1;
    const int bx = blockIdx.x;   // n-block (0..1)
    const int by = blockIdx.y;   // m-block (0..31)
    const int bz = blockIdx.z;   // k slice

    __shared__ U16 S[4][4096];

    f32x4 acc[4][4];
    #pragma unroll
    for (int a = 0; a < 4; ++a)
        #pragma unroll
        for (int b = 0; b < 4; ++b) { f32x4 z = {0.f,0.f,0.f,0.f}; acc[a][b] = z; }

    const int k0beg = bz * klen;
    for (int k0 = k0beg; k0 < k0beg + klen; k0 += 32) {
        __syncthreads();
        const int jb = k0 >> 7, kin = k0 & 127;
        const size_t tb = ((size_t)jb * 32 + by) * 16384;
        #pragma unroll
        for (int h = 0; h < 2; ++h) {
            const int sb   = wid * 128 + h * 64;
            const int slot = sb + lane;
            const int row  = slot & 127, kg = slot >> 7;
            glds16(Wh  + tb + (size_t)row*128 + kin + kg*8,                    &S[0][(size_t)sb * 8]);
            glds16(Wl  + tb + (size_t)row*128 + kin + kg*8,                    &S[1][(size_t)sb * 8]);
            glds16(Xth + (size_t)(bx*128 + row)*NPTS + ch*CHJ + k0 + kg*8,     &S[2][(size_t)sb * 8]);
            glds16(Xtl + (size_t)(bx*128 + row)*NPTS + ch*CHJ + k0 + kg*8,     &S[3][(size_t)sb * 8]);
        }
        __syncthreads();
        bf16x8 fah[4], fal[4], fbh[4], fbl[4];
        const int roff = (lane >> 4) * 128 + (lane & 15);
        #pragma unroll
        for (int f = 0; f < 4; ++f) {
            const int sA = roff + wr*64 + f*16;
            const int sB = roff + wc*64 + f*16;
            fah[f] = *(const bf16x8*)&S[0][(size_t)sA * 8];
            fal[f] = *(const bf16x8*)&S[1][(size_t)sA * 8];
            fbh[f] = *(const bf16x8*)&S[2][(size_t)sB * 8];
            fbl[f] = *(const bf16x8*)&S[3][(size_t)sB * 8];
        }
        #pragma unroll
        for (int a = 0; a < 4; ++a)
            #pragma unroll
            for (int b = 0; b < 4; ++b) {
                acc[a][b] = __builtin_amdgcn_mfma_f32_16x16x32_bf16(fah[a], fbh[b], acc[a][b], 0,0,0);
                acc[a][b] = __builtin_amdgcn_mfma_f32_16x16x32_bf16(fah[a], fbl[b], acc[a][b], 0,0,0);
                acc[a][b] = __builtin_amdgcn_mfma_f32_16x16x32_bf16(fal[a], fbh[b], acc[a][b], 0,0,0);
            }
    }

    const int m0 = by*128 + wr*64;
    const int d0 = bx*128 + wc*64;
    #pragma unroll
    for (int a = 0; a < 4; ++a)
        #pragma unroll
        for (int b = 0; b < 4; ++b)
            #pragma unroll
            for (int i = 0; i < 4; ++i) {
                int m = m0 + a*16 + (lane>>4)*4 + i;
                int d = d0 + b*16 + (lane & 15);
                size_t off = ((size_t)bz*NPTS + m)*DIM + d;
                float v = acc[a][b][i];
                if (!first) v += cnum[off];
                cnum[off] = v;
            }
}

// ---------------- reduce: cnew = cnum/rowsum, shift ----------------
__global__ void reduceK(const float* __restrict__ psum, const float* __restrict__ cnum,
                        const float* __restrict__ c, float* __restrict__ cnew,
                        const int* __restrict__ done, int* __restrict__ shiftb, int spl)
{
    if (*done) return;
    int m = blockIdx.x, t = threadIdx.x;
    __shared__ float rs[64];
    __shared__ float red[256];
    if (t < 64) rs[t] = psum[(size_t)t*NPTS + m];
    __syncthreads();
    if (t < 16) rs[t] = rs[t] + rs[t+16] + rs[t+32] + rs[t+48];
    __syncthreads();
    if (t == 0) { float s = 0.f; for (int k = 0; k < 16; ++k) s += rs[k]; rs[0] = s; }
    __syncthreads();
    float rowsum = rs[0];
    float num = 0.f;
    for (int s = 0; s < spl; ++s) num += cnum[((size_t)s*NPTS + m)*DIM + t];
    float cn = num / rowsum;
    cnew[(size_t)m*DIM + t] = cn;
    float d = cn - c[(size_t)m*DIM + t];
    red[t] = d*d; __syncthreads();
    for (int st = 128; st > 0; st >>= 1) { if (t < st) red[t] += red[t+st]; __syncthreads(); }
    if (t == 0) atomicMax(shiftb, __float_as_int(sqrtf(red[0])));
}

__global__ void flagK(int* done, int* shiftb) {
    float sh = __int_as_float(*shiftb);
    if (!*done && sh < 1e-5f) *done = 1;
    *shiftb = 0;
}

__global__ void finalK(const int* __restrict__ done, const float* __restrict__ c,
                       const float* __restrict__ cnew, float* __restrict__ out) {
    int i = blockIdx.x*256 + threadIdx.x;
    out[i] = (*done) ? c[i] : cnew[i];
}

__global__ void normcK(const float* __restrict__ cen, float* __restrict__ chat) {
    int row = blockIdx.x, t = threadIdx.x;
    float v = cen[(size_t)row*DIM + t];
    __shared__ float red[256];
    red[t] = v*v; __syncthreads();
    for (int s = 128; s > 0; s >>= 1) { if (t < s) red[t] += red[t+s]; __syncthreads(); }
    float rn = 1.0f / fmaxf(sqrtf(red[0]), EPSN);
    chat[(size_t)row*DIM + t] = v*rn;
}

// ---------------- NMS (fp32, unchanged semantics from R1 pass) ----------------
#define KC 32
__global__ __launch_bounds__(256) void argminK(
    const float* __restrict__ chat, const float* __restrict__ xhat,
    float* __restrict__ aval, int* __restrict__ aidx)
{
    const int P  = blockIdx.x * 64;
    const int ms = blockIdx.y;
    const int M0 = ms * (NPTS/ASPL);
    const int tid = threadIdx.x;
    const int tx = tid & 15, ty = tid >> 4;

    __shared__ float A[KC][68];
    __shared__ float B[KC][68];
    __shared__ float mv[16][65];
    __shared__ int   mi[16][65];

    float bv[4] = {3.4e38f,3.4e38f,3.4e38f,3.4e38f};
    int   bm[4] = {0,0,0,0};

    for (int mt = 0; mt < (NPTS/ASPL)/64; ++mt) {
        const int M = M0 + mt*64;
        float s[4][4];
        #pragma unroll
        for (int a=0;a<4;a++){ 
            #pragma unroll
            for (int b2=0;b2<4;b2++) s[a][b2]=0.f; }
        for (int kc = 0; kc < DIM; kc += KC) {
            {
                int i = tid >> 2, q = tid & 3;
                const float* pA = chat + (size_t)(M+i)*DIM + kc + q*4;
                float4 a0 = *(const float4*)pA;
                float4 a1 = *(const float4*)(pA + 16);
                A[q*4+0][i]=a0.x; A[q*4+1][i]=a0.y; A[q*4+2][i]=a0.z; A[q*4+3][i]=a0.w;
                A[q*4+16][i]=a1.x; A[q*4+17][i]=a1.y; A[q*4+18][i]=a1.z; A[q*4+19][i]=a1.w;
                const float* pB = xhat + (size_t)(P+i)*DIM + kc + q*4;
                float4 b0 = *(const float4*)pB;
                float4 b1 = *(const float4*)(pB + 16);
                B[q*4+0][i]=b0.x; B[q*4+1][i]=b0.y; B[q*4+2][i]=b0.z; B[q*4+3][i]=b0.w;
                B[q*4+16][i]=b1.x; B[q*4+17][i]=b1.y; B[q*4+18][i]=b1.z; B[q*4+19][i]=b1.w;
            }
            __syncthreads();
            #pragma unroll
            for (int k = 0; k < KC; ++k) {
                float av[4], bb[4];
                *(float4*)av = *(const float4*)&A[k][ty*4];
                *(float4*)bb = *(const float4*)&B[k][tx*4];
                #pragma unroll
                for (int a=0;a<4;a++){
                    #pragma unroll
                    for (int b2=0;b2<4;b2++)
                        s[a][b2] = fmaf(av[a], bb[b2], s[a][b2]);
                }
            }
            __syncthreads();
        }
        #pragma unroll
        for (int b2=0;b2<4;b2++){
            #pragma unroll
            for (int a=0;a<4;a++){
                float d = 2.0f*(1.0f - s[a][b2]);
                int m = M + ty*4 + a;
                if (d < bv[b2]) { bv[b2]=d; bm[b2]=m; }
            }
        }
    }
    #pragma unroll
    for (int b2=0;b2<4;b2++){ mv[ty][tx*4+b2] = bv[b2]; mi[ty][tx*4+b2] = bm[b2]; }
    __syncthreads();
    if (tid < 64) {
        float v = mv[0][tid]; int m = mi[0][tid];
        for (int k=1;k<16;k++){
            float v2 = mv[k][tid]; int m2 = mi[k][tid];
            if (v2 < v || (v2 == v && m2 < m)) { v=v2; m=m2; }
        }
        aval[(size_t)ms*NPTS + P + tid] = v;
        aidx[(size_t)ms*NPTS + P + tid] = m;
    }
}

__global__ void acombineK(const float* __restrict__ aval, const int* __restrict__ aidx,
                          int* __restrict__ counts)
{
    int p = blockIdx.x*256 + threadIdx.x;
    float bv = 3.4e38f; int bm = 1<<30;
    for (int s = 0; s < ASPL; ++s) {
        float v = aval[(size_t)s*NPTS + p]; int m = aidx[(size_t)s*NPTS + p];
        if (v < bv || (v == bv && m < bm)) { bv=v; bm=m; }
    }
    atomicAdd(&counts[bm], 1);
}

__global__ __launch_bounds__(256) void ccK(
    const float* __restrict__ chat, const int* __restrict__ counts,
    const float* __restrict__ sigma,
    float* __restrict__ cval, int* __restrict__ cidx)
{
    const int Mrow = blockIdx.x * 64;
    const int js   = blockIdx.y;
    const int J0   = js * (NPTS/ASPL);
    const float bw = *sigma;
    const int tid = threadIdx.x;
    const int tx = tid & 15, ty = tid >> 4;

    __shared__ float A[KC][68];
    __shared__ float B[KC][68];
    __shared__ float cnt[64];
    __shared__ float mv[64][17];
    __shared__ int   mi[64][17];

    float bvv[4] = {-1.f,-1.f,-1.f,-1.f};
    int   bjj[4] = {1<<30,1<<30,1<<30,1<<30};

    for (int jt = 0; jt < (NPTS/ASPL)/64; ++jt) {
        const int J = J0 + jt*64;
        if (tid < 64) cnt[tid] = (float)counts[J + tid];
        float s[4][4];
        #pragma unroll
        for (int a=0;a<4;a++){
            #pragma unroll
            for (int b2=0;b2<4;b2++) s[a][b2]=0.f; }
        for (int kc = 0; kc < DIM; kc += KC) {
            {
                int i = tid >> 2, q = tid & 3;
                const float* pA = chat + (size_t)(Mrow+i)*DIM + kc + q*4;
                float4 a0 = *(const float4*)pA;
                float4 a1 = *(const float4*)(pA + 16);
                A[q*4+0][i]=a0.x; A[q*4+1][i]=a0.y; A[q*4+2][i]=a0.z; A[q*4+3][i]=a0.w;
                A[q*4+16][i]=a1.x; A[q*4+17][i]=a1.y; A[q*4+18][i]=a1.z; A[q*4+19][i]=a1.w;
                const float* pB = chat + (size_t)(J+i)*DIM + kc + q*4;
                float4 b0 = *(const float4*)pB;
                float4 b1 = *(const float4*)(pB + 16);
                B[q*4+0][i]=b0.x; B[q*4+1][i]=b0.y; B[q*4+2][i]=b0.z; B[q*4+3][i]=b0.w;
                B[q*4+16][i]=b1.x; B[q*4+17][i]=b1.y; B[q*4+18][i]=b1.z; B[q*4+19][i]=b1.w;
            }
            __syncthreads();
            #pragma unroll
            for (int k = 0; k < KC; ++k) {
                float av[4], bb[4];
                *(float4*)av = *(const float4*)&A[k][ty*4];
                *(float4*)bb = *(const float4*)&B[k][tx*4];
                #pragma unroll
                for (int a=0;a<4;a++){
                    #pragma unroll
                    for (int b2=0;b2<4;b2++)
                        s[a][b2] = fmaf(av[a], bb[b2], s[a][b2]);
                }
            }
            __syncthreads();
        }
        #pragma unroll
        for (int a=0;a<4;a++){
            #pragma unroll
            for (int b2=0;b2<4;b2++){
                float d = 2.0f*(1.0f - s[a][b2]);
                float val = (d < bw) ? cnt[tx*4+b2] : 0.0f;
                int j = J + tx*4 + b2;
                if (val > bvv[a] || (val == bvv[a] && j < bjj[a])) { bvv[a]=val; bjj[a]=j; }
            }
        }
        __syncthreads();
    }
    #pragma unroll
    for (int a=0;a<4;a++){ mv[ty*4+a][tx] = bvv[a]; mi[ty*4+a][tx] = bjj[a]; }
    __syncthreads();
    if (tid < 64) {
        float v = mv[tid][0]; int j = mi[tid][0];
        for (int k=1;k<16;k++){
            float v2 = mv[tid][k]; int j2 = mi[tid][k];
            if (v2 > v || (v2 == v && j2 < j)) { v=v2; j=j2; }
        }
        cval[(size_t)js*NPTS + Mrow + tid] = v;
        cidx[(size_t)js*NPTS + Mrow + tid] = j;
    }
}

__global__ void ccombineK(const float* __restrict__ cval, const int* __restrict__ cidx,
                          const int* __restrict__ counts, int* __restrict__ keep)
{
    int m = blockIdx.x*256 + threadIdx.x;
    float bv = -1.0f; int bj = 1<<30;
    for (int s = 0; s < ASPL; ++s) {
        float v = cval[(size_t)s*NPTS + m]; int j = cidx[(size_t)s*NPTS + m];
        if (v > bv || (v == bv && j < bj)) { bv=v; bj=j; }
    }
    if (counts[m] > 0) atomicOr(&keep[bj], 1);
}

__global__ void keepwriteK(const int* __restrict__ keep, float* __restrict__ out)
{
    int i = blockIdx.x*256 + threadIdx.x;
    out[(size_t)NPTS*DIM + i] = keep[i] ? 1.0f : 0.0f;
}

// ---------------- host ----------------
extern "C" void kernel_launch(void* const* d_in, const int* in_sizes, int n_in,
                              void* d_out, int out_size, void* d_ws, size_t ws_size,
                              hipStream_t stream)
{
    const float* x     = (const float*)d_in[0];
    const float* sigma = (const float*)d_in[1];
    float* out = (float*)d_out;

    const size_t ND4 = (size_t)NPTS * DIM * 4;   // 4 MB
    const size_t NDu = (size_t)NPTS * DIM * 2;   // 2 MB

    struct Cfg { int nch, spl; };
    const Cfg cfgs[] = {{1,4},{2,4},{4,4},{8,4},{8,2},{16,2},{16,1},{32,1}};

    int NCH = 32, SPL = 1;
    size_t o_xh=0,o_xl=0,o_xf=0,o_xth=0,o_xtl=0,o_chh=0,o_chl=0,o_c=0,o_cn=0,
           o_cnum=0,o_psum=0,o_wh=0,o_wl=0,o_aval=0,o_aidx=0,o_cval=0,o_cidx=0,
           o_counts=0,o_keep=0,o_done=0,o_shift=0;

    for (int ci = 0; ci < (int)(sizeof(cfgs)/sizeof(cfgs[0])); ++ci) {
        int nch = cfgs[ci].nch, spl = cfgs[ci].spl;
        size_t CHJ = NPTS / nch;
        size_t off = 0;
        auto take = [&](size_t nb) { size_t a = off; off += (nb + 255) & ~(size_t)255; return a; };
        o_xh  = take(NDu);  o_xl  = take(NDu);  o_xf = take(ND4);
        o_xth = take(NDu);  o_xtl = take(NDu);
        o_chh = take(NDu);  o_chl = take(NDu);
        o_c   = take(ND4);  o_cn  = take(ND4);
        o_cnum = take((size_t)spl * ND4);
        o_psum = take((size_t)64 * NPTS * 4);
        o_wh  = take((size_t)NPTS * CHJ * 2);
        o_wl  = take((size_t)NPTS * CHJ * 2);
        o_aval = take((size_t)ASPL*NPTS*4); o_aidx = take((size_t)ASPL*NPTS*4);
        o_cval = take((size_t)ASPL*NPTS*4); o_cidx = take((size_t)ASPL*NPTS*4);
        o_counts = take((size_t)NPTS*4);    o_keep = take((size_t)NPTS*4);
        o_done = take(256); o_shift = take(256);
        NCH = nch; SPL = spl;
        if (off <= ws_size) break;
    }
    const int CHJ  = NPTS / NCH;
    const int JBC  = CHJ / 128;
    const int KLEN = CHJ / SPL;

    char* W = (char*)d_ws;
    U16* xh  = (U16*)(W + o_xh);   U16* xl  = (U16*)(W + o_xl);
    float* xf = (float*)(W + o_xf);
    U16* xth = (U16*)(W + o_xth);  U16* xtl = (U16*)(W + o_xtl);
    U16* chh = (U16*)(W + o_chh);  U16* chl = (U16*)(W + o_chl);
    float* c    = (float*)(W + o_c);
    float* cnew = (float*)(W + o_cn);
    float* cnum = (float*)(W + o_cnum);
    float* psum = (float*)(W + o_psum);
    U16* wh = (U16*)(W + o_wh);    U16* wl = (U16*)(W + o_wl);
    float* aval = (float*)(W + o_aval); int* aidx = (int*)(W + o_aidx);
    float* cval = (float*)(W + o_cval); int* cidx = (int*)(W + o_cidx);
    int* counts = (int*)(W + o_counts); int* keep = (int*)(W + o_keep);
    int* done   = (int*)(W + o_done);   int* shiftb = (int*)(W + o_shift);
    float* chatF = cnum;   // alias: cnum dead after iterations

    initK  <<<dim3(16), dim3(256), 0, stream>>>(counts, keep, done, shiftb);
    normxK <<<dim3(NPTS), dim3(256), 0, stream>>>(x, c, xf, xh, xl);
    transpK<<<dim3(128, 8), dim3(256), 0, stream>>>(x, xth, xtl);

    for (int it = 0; it < MAX_ITERS; ++it) {
        normsplitK<<<dim3(NPTS), dim3(256), 0, stream>>>(c, cnew, chh, chl, done, it > 0);
        for (int ch = 0; ch < NCH; ++ch) {
            simK<<<dim3(JBC, 32), dim3(256), 0, stream>>>(
                chh, chl, xh, xl, wh, wl, psum, done, sigma, ch, CHJ);
            wxK<<<dim3(2, 32, SPL), dim3(256), 0, stream>>>(
                wh, wl, xth, xtl, cnum, done, ch, CHJ, KLEN, ch == 0);
        }
        reduceK<<<dim3(NPTS), dim3(256), 0, stream>>>(psum, cnum, c, cnew, done, shiftb, SPL);
        flagK  <<<dim3(1), dim3(1), 0, stream>>>(done, shiftb);
    }

    finalK<<<dim3(NPTS), dim3(256), 0, stream>>>(done, c, cnew, out);
    normcK<<<dim3(NPTS), dim3(256), 0, stream>>>(out, chatF);

    argminK  <<<dim3(NPTS/64, ASPL), dim3(256), 0, stream>>>(chatF, xf, aval, aidx);
    acombineK<<<dim3(NPTS/256), dim3(256), 0, stream>>>(aval, aidx, counts);
    ccK      <<<dim3(NPTS/64, ASPL), dim3(256), 0, stream>>>(chatF, counts, sigma, cval, cidx);
    ccombineK<<<dim3(NPTS/256), dim3(256), 0, stream>>>(cval, cidx, counts, keep);
    keepwriteK<<<dim3(NPTS/256), dim3(256), 0, stream>>>(keep, out);
}

// Round 3
// 2055.115 us; speedup vs baseline: 2.8145x; 1.0950x over previous
//
#include <hip/hip_runtime.h>
#include <math.h>

#define NPTS 4096
#define DIM  256
#define MAX_ITERS 10
#define EPSN 1e-8f
#define NSPL 16   // splits for NMS kernels

typedef __bf16 bf16x8 __attribute__((ext_vector_type(8)));
typedef float  f32x4  __attribute__((ext_vector_type(4)));
typedef unsigned short u16x8 __attribute__((ext_vector_type(8)));
typedef unsigned short u16x4 __attribute__((ext_vector_type(4)));
typedef unsigned short U16;

__device__ __forceinline__ U16 bf16_rne(float f) {
    unsigned int u = __float_as_uint(f);
    u += 0x7FFFu + ((u >> 16) & 1u);
    return (U16)(u >> 16);
}

__device__ __forceinline__ void glds16(const void* g, void* l) {
    __builtin_amdgcn_global_load_lds(
        (const __attribute__((address_space(1))) unsigned int*)g,
        (__attribute__((address_space(3))) unsigned int*)l,
        16, 0, 0);
}

// ---------------- prep ----------------
__global__ void initK(int* counts, int* keep, int* done, int* shiftb) {
    int i = blockIdx.x * 256 + threadIdx.x;
    if (i < NPTS) { counts[i] = 0; keep[i] = 0; }
    if (i == 0) { *done = 0; *shiftb = 0; }
}

// x -> c (copy), xhat hi/lo splits
__global__ void normxK(const float* __restrict__ x, float* __restrict__ c,
                       U16* __restrict__ xh, U16* __restrict__ xl) {
    int m = blockIdx.x, t = threadIdx.x;
    float v = x[(size_t)m*DIM + t];
    __shared__ float red[256];
    red[t] = v*v; __syncthreads();
    for (int s = 128; s > 0; s >>= 1) { if (t < s) red[t] += red[t+s]; __syncthreads(); }
    float rn = 1.0f / fmaxf(sqrtf(red[0]), EPSN);
    float hv = v*rn;
    U16 hb = bf16_rne(hv);
    float hf = __uint_as_float((unsigned)hb << 16);
    U16 lb = bf16_rne(hv - hf);
    c [(size_t)m*DIM + t] = v;
    xh[(size_t)m*DIM + t] = hb;
    xl[(size_t)m*DIM + t] = lb;
}

// x^T split: Xt[d][p] = x[p][d] as bf16 hi/lo
__global__ void transpK(const float* __restrict__ x, U16* __restrict__ Xth, U16* __restrict__ Xtl) {
    int bm = blockIdx.x, bd = blockIdx.y;
    int t = threadIdx.x;
    __shared__ float sh[32][33];
    int r = t >> 3, cq = (t & 7) * 4;
    float4 v = *(const float4*)&x[(size_t)(bm*32 + r)*DIM + bd*32 + cq];
    sh[r][cq] = v.x; sh[r][cq+1] = v.y; sh[r][cq+2] = v.z; sh[r][cq+3] = v.w;
    __syncthreads();
    int dd = t >> 3, mq = (t & 7) * 4;
    u16x4 h4, l4;
    #pragma unroll
    for (int j = 0; j < 4; ++j) {
        float f = sh[mq + j][dd];
        U16 hb = bf16_rne(f);
        h4[j] = hb;
        l4[j] = bf16_rne(f - __uint_as_float((unsigned)hb << 16));
    }
    size_t off = (size_t)(bd*32 + dd)*NPTS + bm*32 + mq;
    *(u16x4*)&Xth[off] = h4;
    *(u16x4*)&Xtl[off] = l4;
}

// commit (optional) + normalize + split current centroids
__global__ void normsplitK(float* __restrict__ c, const float* __restrict__ cnew,
                           U16* __restrict__ chh, U16* __restrict__ chl,
                           const int* __restrict__ done, int commit) {
    if (*done) return;
    int m = blockIdx.x, t = threadIdx.x;
    float v;
    if (commit) { v = cnew[(size_t)m*DIM + t]; c[(size_t)m*DIM + t] = v; }
    else        { v = c[(size_t)m*DIM + t]; }
    __shared__ float red[256];
    red[t] = v*v; __syncthreads();
    for (int s = 128; s > 0; s >>= 1) { if (t < s) red[t] += red[t+s]; __syncthreads(); }
    float rn = 1.0f / fmaxf(sqrtf(red[0]), EPSN);
    float hv = v*rn;
    U16 hb = bf16_rne(hv);
    float hf = __uint_as_float((unsigned)hb << 16);
    U16 lb = bf16_rne(hv - hf);
    chh[(size_t)m*DIM + t] = hb;
    chl[(size_t)m*DIM + t] = lb;
}

// normalize final centroids -> hi/lo splits (for NMS)
__global__ void normfinalK(const float* __restrict__ cen,
                           U16* __restrict__ hh, U16* __restrict__ ll) {
    int m = blockIdx.x, t = threadIdx.x;
    float v = cen[(size_t)m*DIM + t];
    __shared__ float red[256];
    red[t] = v*v; __syncthreads();
    for (int s = 128; s > 0; s >>= 1) { if (t < s) red[t] += red[t+s]; __syncthreads(); }
    float rn = 1.0f / fmaxf(sqrtf(red[0]), EPSN);
    float hv = v*rn;
    U16 hb = bf16_rne(hv);
    float hf = __uint_as_float((unsigned)hb << 16);
    U16 lb = bf16_rne(hv - hf);
    hh[(size_t)m*DIM + t] = hb;
    ll[(size_t)m*DIM + t] = lb;
}

// ---------------- simK: S = chat . xhat^T (split-bf16 MFMA), epilogue exp -> W hi/lo + psum ----------------
__global__ __launch_bounds__(256) void simK(
    const U16* __restrict__ Ahg, const U16* __restrict__ Alg,
    const U16* __restrict__ Bhg, const U16* __restrict__ Blg,
    U16* __restrict__ Wh, U16* __restrict__ Wl,
    float* __restrict__ psum, const int* __restrict__ done,
    const float* __restrict__ sigma, int ch, int CHJ)
{
    if (*done) return;
    const int tid = threadIdx.x;
    const int lane = tid & 63, wid = tid >> 6;
    const int wr = wid & 1, wc = wid >> 1;
    const int I  = blockIdx.y * 128;
    const int Jl = blockIdx.x * 128;
    const int Jg = ch * CHJ + Jl;

    __shared__ union {
        U16 st[4][4096];
        unsigned int bounce[128 * 65];
    } L;

    f32x4 acc[4][4];
    #pragma unroll
    for (int a = 0; a < 4; ++a)
        #pragma unroll
        for (int b = 0; b < 4; ++b) { f32x4 z = {0.f,0.f,0.f,0.f}; acc[a][b] = z; }

    const float ig = 1.0f / (2.0f * (*sigma) * (*sigma));

    for (int k0 = 0; k0 < DIM; k0 += 32) {
        __syncthreads();
        #pragma unroll
        for (int h = 0; h < 2; ++h) {
            const int sb   = wid * 128 + h * 64;
            const int slot = sb + lane;
            const int row  = slot & 127, kg = slot >> 7;
            const int col  = k0 + kg * 8;
            glds16(Ahg + (size_t)(I  + row)*DIM + col, &L.st[0][(size_t)sb * 8]);
            glds16(Alg + (size_t)(I  + row)*DIM + col, &L.st[1][(size_t)sb * 8]);
            glds16(Bhg + (size_t)(Jg + row)*DIM + col, &L.st[2][(size_t)sb * 8]);
            glds16(Blg + (size_t)(Jg + row)*DIM + col, &L.st[3][(size_t)sb * 8]);
        }
        __syncthreads();
        bf16x8 fah[4], fal[4], fbh[4], fbl[4];
        const int roff = (lane >> 4) * 128 + (lane & 15);
        #pragma unroll
        for (int f = 0; f < 4; ++f) {
            const int sA = roff + wr*64 + f*16;
            const int sB = roff + wc*64 + f*16;
            fah[f] = *(const bf16x8*)&L.st[0][(size_t)sA * 8];
            fal[f] = *(const bf16x8*)&L.st[1][(size_t)sA * 8];
            fbh[f] = *(const bf16x8*)&L.st[2][(size_t)sB * 8];
            fbl[f] = *(const bf16x8*)&L.st[3][(size_t)sB * 8];
        }
        #pragma unroll
        for (int a = 0; a < 4; ++a)
            #pragma unroll
            for (int b = 0; b < 4; ++b) {
                acc[a][b] = __builtin_amdgcn_mfma_f32_16x16x32_bf16(fah[a], fbh[b], acc[a][b], 0,0,0);
                acc[a][b] = __builtin_amdgcn_mfma_f32_16x16x32_bf16(fah[a], fbl[b], acc[a][b], 0,0,0);
                acc[a][b] = __builtin_amdgcn_mfma_f32_16x16x32_bf16(fal[a], fbh[b], acc[a][b], 0,0,0);
            }
    }

    float rsum[4][4];
    unsigned int pk[4][4][4];
    #pragma unroll
    for (int a = 0; a < 4; ++a)
        #pragma unroll
        for (int i = 0; i < 4; ++i) rsum[a][i] = 0.f;
    #pragma unroll
    for (int a = 0; a < 4; ++a)
        #pragma unroll
        for (int b = 0; b < 4; ++b)
            #pragma unroll
            for (int i = 0; i < 4; ++i) {
                float w = __expf(2.0f * (acc[a][b][i] - 1.0f) * ig);
                U16 hb = bf16_rne(w);
                float hf = __uint_as_float((unsigned)hb << 16);
                U16 lb = bf16_rne(w - hf);
                pk[a][b][i] = ((unsigned)lb << 16) | (unsigned)hb;
                rsum[a][i] += w;
            }
    #pragma unroll
    for (int msk = 1; msk < 16; msk <<= 1)
        #pragma unroll
        for (int a = 0; a < 4; ++a)
            #pragma unroll
            for (int i = 0; i < 4; ++i)
                rsum[a][i] += __shfl_xor(rsum[a][i], msk, 64);
    if ((lane & 15) == 0) {
        int cb = (Jg >> 6) + wc;
        #pragma unroll
        for (int a = 0; a < 4; ++a)
            #pragma unroll
            for (int i = 0; i < 4; ++i)
                psum[(size_t)cb*NPTS + I + wr*64 + a*16 + (lane>>4)*4 + i] = rsum[a][i];
    }

    const size_t tbase = ((size_t)blockIdx.x * 32 + blockIdx.y) * 16384;
    __syncthreads();
    #pragma unroll
    for (int q = 0; q < 2; ++q) {
        if (wc == q) {
            #pragma unroll
            for (int a = 0; a < 4; ++a)
                #pragma unroll
                for (int b = 0; b < 4; ++b)
                    #pragma unroll
                    for (int i = 0; i < 4; ++i) {
                        int row = wr*64 + a*16 + (lane>>4)*4 + i;
                        int col = b*16 + (lane & 15);
                        L.bounce[row*65 + col] = pk[a][b][i];
                    }
        }
        __syncthreads();
        {
            int row = tid >> 1, half = tid & 1;
            int cbase = half * 32;
            #pragma unroll
            for (int s = 0; s < 4; ++s) {
                unsigned int u[8];
                #pragma unroll
                for (int j = 0; j < 8; ++j) u[j] = L.bounce[row*65 + cbase + s*8 + j];
                u16x8 hh, ll;
                #pragma unroll
                for (int j = 0; j < 8; ++j) { hh[j] = (U16)(u[j] & 0xFFFFu); ll[j] = (U16)(u[j] >> 16); }
                size_t off = tbase + (size_t)row*128 + q*64 + cbase + s*8;
                *(u16x8*)&Wh[off] = hh;
                *(u16x8*)&Wl[off] = ll;
            }
        }
        __syncthreads();
    }
}

// ---------------- wxK: cnum[slice] (+)= W . X ----------------
__global__ __launch_bounds__(256) void wxK(
    const U16* __restrict__ Wh, const U16* __restrict__ Wl,
    const U16* __restrict__ Xth, const U16* __restrict__ Xtl,
    float* __restrict__ cnum, const int* __restrict__ done,
    int ch, int CHJ, int klen, int first)
{
    if (*done) return;
    const int tid = threadIdx.x;
    const int lane = tid & 63, wid = tid >> 6;
    const int wr = wid & 1, wc = wid >> 1;
    const int bx = blockIdx.x;
    const int by = blockIdx.y;
    const int bz = blockIdx.z;

    __shared__ U16 S[4][4096];

    f32x4 acc[4][4];
    #pragma unroll
    for (int a = 0; a < 4; ++a)
        #pragma unroll
        for (int b = 0; b < 4; ++b) { f32x4 z = {0.f,0.f,0.f,0.f}; acc[a][b] = z; }

    const int k0beg = bz * klen;
    for (int k0 = k0beg; k0 < k0beg + klen; k0 += 32) {
        __syncthreads();
        const int jb = k0 >> 7, kin = k0 & 127;
        const size_t tb = ((size_t)jb * 32 + by) * 16384;
        #pragma unroll
        for (int h = 0; h < 2; ++h) {
            const int sb   = wid * 128 + h * 64;
            const int slot = sb + lane;
            const int row  = slot & 127, kg = slot >> 7;
            glds16(Wh  + tb + (size_t)row*128 + kin + kg*8,                &S[0][(size_t)sb * 8]);
            glds16(Wl  + tb + (size_t)row*128 + kin + kg*8,                &S[1][(size_t)sb * 8]);
            glds16(Xth + (size_t)(bx*128 + row)*NPTS + ch*CHJ + k0 + kg*8, &S[2][(size_t)sb * 8]);
            glds16(Xtl + (size_t)(bx*128 + row)*NPTS + ch*CHJ + k0 + kg*8, &S[3][(size_t)sb * 8]);
        }
        __syncthreads();
        bf16x8 fah[4], fal[4], fbh[4], fbl[4];
        const int roff = (lane >> 4) * 128 + (lane & 15);
        #pragma unroll
        for (int f = 0; f < 4; ++f) {
            const int sA = roff + wr*64 + f*16;
            const int sB = roff + wc*64 + f*16;
            fah[f] = *(const bf16x8*)&S[0][(size_t)sA * 8];
            fal[f] = *(const bf16x8*)&S[1][(size_t)sA * 8];
            fbh[f] = *(const bf16x8*)&S[2][(size_t)sB * 8];
            fbl[f] = *(const bf16x8*)&S[3][(size_t)sB * 8];
        }
        #pragma unroll
        for (int a = 0; a < 4; ++a)
            #pragma unroll
            for (int b = 0; b < 4; ++b) {
                acc[a][b] = __builtin_amdgcn_mfma_f32_16x16x32_bf16(fah[a], fbh[b], acc[a][b], 0,0,0);
                acc[a][b] = __builtin_amdgcn_mfma_f32_16x16x32_bf16(fah[a], fbl[b], acc[a][b], 0,0,0);
                acc[a][b] = __builtin_amdgcn_mfma_f32_16x16x32_bf16(fal[a], fbh[b], acc[a][b], 0,0,0);
            }
    }

    const int m0 = by*128 + wr*64;
    const int d0 = bx*128 + wc*64;
    #pragma unroll
    for (int a = 0; a < 4; ++a)
        #pragma unroll
        for (int b = 0; b < 4; ++b)
            #pragma unroll
            for (int i = 0; i < 4; ++i) {
                int m = m0 + a*16 + (lane>>4)*4 + i;
                int d = d0 + b*16 + (lane & 15);
                size_t off = ((size_t)bz*NPTS + m)*DIM + d;
                float v = acc[a][b][i];
                if (!first) v += cnum[off];
                cnum[off] = v;
            }
}

// ---------------- reduce: cnew = cnum/rowsum, shift ----------------
__global__ void reduceK(const float* __restrict__ psum, const float* __restrict__ cnum,
                        const float* __restrict__ c, float* __restrict__ cnew,
                        const int* __restrict__ done, int* __restrict__ shiftb, int spl)
{
    if (*done) return;
    int m = blockIdx.x, t = threadIdx.x;
    __shared__ float rs[64];
    __shared__ float red[256];
    if (t < 64) rs[t] = psum[(size_t)t*NPTS + m];
    __syncthreads();
    if (t < 16) rs[t] = rs[t] + rs[t+16] + rs[t+32] + rs[t+48];
    __syncthreads();
    if (t == 0) { float s = 0.f; for (int k = 0; k < 16; ++k) s += rs[k]; rs[0] = s; }
    __syncthreads();
    float rowsum = rs[0];
    float num = 0.f;
    for (int s = 0; s < spl; ++s) num += cnum[((size_t)s*NPTS + m)*DIM + t];
    float cn = num / rowsum;
    cnew[(size_t)m*DIM + t] = cn;
    float d = cn - c[(size_t)m*DIM + t];
    red[t] = d*d; __syncthreads();
    for (int st = 128; st > 0; st >>= 1) { if (t < st) red[t] += red[t+st]; __syncthreads(); }
    if (t == 0) atomicMax(shiftb, __float_as_int(sqrtf(red[0])));
}

__global__ void flagK(int* done, int* shiftb) {
    float sh = __int_as_float(*shiftb);
    if (!*done && sh < 1e-5f) *done = 1;
    *shiftb = 0;
}

__global__ void finalK(const int* __restrict__ done, const float* __restrict__ c,
                       const float* __restrict__ cnew, float* __restrict__ out) {
    int i = blockIdx.x*256 + threadIdx.x;
    out[i] = (*done) ? c[i] : cnew[i];
}

// ---------------- NMS: MFMA per-point argmin over centroids ----------------
// A rows = points (xhat), B cols = centroids (chat). C[p][m]; reduce over cols.
__global__ __launch_bounds__(256) void argminMK(
    const U16* __restrict__ Ph, const U16* __restrict__ Pl,
    const U16* __restrict__ Ch, const U16* __restrict__ Cl,
    float* __restrict__ aval, int* __restrict__ aidx)
{
    const int tid = threadIdx.x;
    const int lane = tid & 63, wid = tid >> 6;
    const int wr = wid & 1, wc = wid >> 1;
    const int P  = blockIdx.x * 128;
    const int ms = blockIdx.y;
    const int M0 = ms * (NPTS / NSPL);

    __shared__ U16 S[4][4096];
    __shared__ float fmv[128][2];
    __shared__ int   fmi[128][2];

    float pv[16];
    int   pm[16];
    #pragma unroll
    for (int s = 0; s < 16; ++s) { pv[s] = 3.4e38f; pm[s] = 0; }

    for (int mt = 0; mt < (NPTS/NSPL)/128; ++mt) {
        const int M = M0 + mt*128;
        f32x4 acc[4][4];
        #pragma unroll
        for (int a = 0; a < 4; ++a)
            #pragma unroll
            for (int b = 0; b < 4; ++b) { f32x4 z = {0.f,0.f,0.f,0.f}; acc[a][b] = z; }

        for (int k0 = 0; k0 < DIM; k0 += 32) {
            __syncthreads();
            #pragma unroll
            for (int h = 0; h < 2; ++h) {
                const int sb   = wid * 128 + h * 64;
                const int slot = sb + lane;
                const int row  = slot & 127, kg = slot >> 7;
                const int col  = k0 + kg * 8;
                glds16(Ph + (size_t)(P + row)*DIM + col, &S[0][(size_t)sb * 8]);
                glds16(Pl + (size_t)(P + row)*DIM + col, &S[1][(size_t)sb * 8]);
                glds16(Ch + (size_t)(M + row)*DIM + col, &S[2][(size_t)sb * 8]);
                glds16(Cl + (size_t)(M + row)*DIM + col, &S[3][(size_t)sb * 8]);
            }
            __syncthreads();
            bf16x8 fah[4], fal[4], fbh[4], fbl[4];
            const int roff = (lane >> 4) * 128 + (lane & 15);
            #pragma unroll
            for (int f = 0; f < 4; ++f) {
                const int sA = roff + wr*64 + f*16;
                const int sB = roff + wc*64 + f*16;
                fah[f] = *(const bf16x8*)&S[0][(size_t)sA * 8];
                fal[f] = *(const bf16x8*)&S[1][(size_t)sA * 8];
                fbh[f] = *(const bf16x8*)&S[2][(size_t)sB * 8];
                fbl[f] = *(const bf16x8*)&S[3][(size_t)sB * 8];
            }
            #pragma unroll
            for (int a = 0; a < 4; ++a)
                #pragma unroll
                for (int b = 0; b < 4; ++b) {
                    acc[a][b] = __builtin_amdgcn_mfma_f32_16x16x32_bf16(fah[a], fbh[b], acc[a][b], 0,0,0);
                    acc[a][b] = __builtin_amdgcn_mfma_f32_16x16x32_bf16(fah[a], fbl[b], acc[a][b], 0,0,0);
                    acc[a][b] = __builtin_amdgcn_mfma_f32_16x16x32_bf16(fal[a], fbh[b], acc[a][b], 0,0,0);
                }
        }
        #pragma unroll
        for (int a = 0; a < 4; ++a)
            #pragma unroll
            for (int i = 0; i < 4; ++i) {
                const int s = a*4 + i;
                #pragma unroll
                for (int b = 0; b < 4; ++b) {
                    float d = 2.0f*(1.0f - acc[a][b][i]);
                    int m = M + wc*64 + b*16 + (lane & 15);
                    if (d < pv[s] || (d == pv[s] && m < pm[s])) { pv[s]=d; pm[s]=m; }
                }
            }
    }
    #pragma unroll
    for (int msk = 1; msk < 16; msk <<= 1)
        #pragma unroll
        for (int s = 0; s < 16; ++s) {
            float v2 = __shfl_xor(pv[s], msk, 64);
            int   m2 = __shfl_xor(pm[s], msk, 64);
            if (v2 < pv[s] || (v2 == pv[s] && m2 < pm[s])) { pv[s]=v2; pm[s]=m2; }
        }
    if ((lane & 15) == 0) {
        #pragma unroll
        for (int a = 0; a < 4; ++a)
            #pragma unroll
            for (int i = 0; i < 4; ++i) {
                int row = wr*64 + a*16 + (lane>>4)*4 + i;
                fmv[row][wc] = pv[a*4+i];
                fmi[row][wc] = pm[a*4+i];
            }
    }
    __syncthreads();
    if (tid < 128) {
        float v = fmv[tid][0]; int m = fmi[tid][0];
        float v1 = fmv[tid][1]; int m1 = fmi[tid][1];
        if (v1 < v || (v1 == v && m1 < m)) { v=v1; m=m1; }
        aval[(size_t)ms*NPTS + P + tid] = v;
        aidx[(size_t)ms*NPTS + P + tid] = m;
    }
}

__global__ void acombineK(const float* __restrict__ aval, const int* __restrict__ aidx,
                          int* __restrict__ counts)
{
    int p = blockIdx.x*256 + threadIdx.x;
    float bv = 3.4e38f; int bm = 1<<30;
    for (int s = 0; s < NSPL; ++s) {
        float v = aval[(size_t)s*NPTS + p]; int m = aidx[(size_t)s*NPTS + p];
        if (v < bv || (v == bv && m < bm)) { bv=v; bm=m; }
    }
    atomicAdd(&counts[bm], 1);
}

// ---------------- NMS: MFMA per-centroid argmax of close*counts ----------------
// A rows = centroids m (chat), B cols = centroids j (chat). C[m][j]; reduce over cols.
__global__ __launch_bounds__(256) void ccMK(
    const U16* __restrict__ Ch, const U16* __restrict__ Cl,
    const int* __restrict__ counts, const float* __restrict__ sigma,
    float* __restrict__ cval, int* __restrict__ cidx)
{
    const int tid = threadIdx.x;
    const int lane = tid & 63, wid = tid >> 6;
    const int wr = wid & 1, wc = wid >> 1;
    const int Mrow = blockIdx.x * 128;
    const int js   = blockIdx.y;
    const int J0   = js * (NPTS / NSPL);
    const float bw = *sigma;

    __shared__ U16 S[4][4096];
    __shared__ float gmv[128][2];
    __shared__ int   gmi[128][2];
    __shared__ float scnt[128];

    float mvv[16];
    int   mjj[16];
    #pragma unroll
    for (int s = 0; s < 16; ++s) { mvv[s] = -1.f; mjj[s] = 1<<30; }

    for (int jt = 0; jt < (NPTS/NSPL)/128; ++jt) {
        const int J = J0 + jt*128;
        __syncthreads();                     // protect scnt from previous tile's readers
        if (tid < 128) scnt[tid] = (float)counts[J + tid];
        f32x4 acc[4][4];
        #pragma unroll
        for (int a = 0; a < 4; ++a)
            #pragma unroll
            for (int b = 0; b < 4; ++b) { f32x4 z = {0.f,0.f,0.f,0.f}; acc[a][b] = z; }

        for (int k0 = 0; k0 < DIM; k0 += 32) {
            __syncthreads();
            #pragma unroll
            for (int h = 0; h < 2; ++h) {
                const int sb   = wid * 128 + h * 64;
                const int slot = sb + lane;
                const int row  = slot & 127, kg = slot >> 7;
                const int col  = k0 + kg * 8;
                glds16(Ch + (size_t)(Mrow + row)*DIM + col, &S[0][(size_t)sb * 8]);
                glds16(Cl + (size_t)(Mrow + row)*DIM + col, &S[1][(size_t)sb * 8]);
                glds16(Ch + (size_t)(J + row)*DIM + col,    &S[2][(size_t)sb * 8]);
                glds16(Cl + (size_t)(J + row)*DIM + col,    &S[3][(size_t)sb * 8]);
            }
            __syncthreads();
            bf16x8 fah[4], fal[4], fbh[4], fbl[4];
            const int roff = (lane >> 4) * 128 + (lane & 15);
            #pragma unroll
            for (int f = 0; f < 4; ++f) {
                const int sA = roff + wr*64 + f*16;
                const int sB = roff + wc*64 + f*16;
                fah[f] = *(const bf16x8*)&S[0][(size_t)sA * 8];
                fal[f] = *(const bf16x8*)&S[1][(size_t)sA * 8];
                fbh[f] = *(const bf16x8*)&S[2][(size_t)sB * 8];
                fbl[f] = *(const bf16x8*)&S[3][(size_t)sB * 8];
            }
            #pragma unroll
            for (int a = 0; a < 4; ++a)
                #pragma unroll
                for (int b = 0; b < 4; ++b) {
                    acc[a][b] = __builtin_amdgcn_mfma_f32_16x16x32_bf16(fah[a], fbh[b], acc[a][b], 0,0,0);
                    acc[a][b] = __builtin_amdgcn_mfma_f32_16x16x32_bf16(fah[a], fbl[b], acc[a][b], 0,0,0);
                    acc[a][b] = __builtin_amdgcn_mfma_f32_16x16x32_bf16(fal[a], fbh[b], acc[a][b], 0,0,0);
                }
        }
        #pragma unroll
        for (int a = 0; a < 4; ++a)
            #pragma unroll
            for (int i = 0; i < 4; ++i) {
                const int s = a*4 + i;
                #pragma unroll
                for (int b = 0; b < 4; ++b) {
                    float d = 2.0f*(1.0f - acc[a][b][i]);
                    int jl = wc*64 + b*16 + (lane & 15);
                    float val = (d < bw) ? scnt[jl] : 0.0f;
                    int j = J + jl;
                    if (val > mvv[s] || (val == mvv[s] && j < mjj[s])) { mvv[s]=val; mjj[s]=j; }
                }
            }
    }
    #pragma unroll
    for (int msk = 1; msk < 16; msk <<= 1)
        #pragma unroll
        for (int s = 0; s < 16; ++s) {
            float v2 = __shfl_xor(mvv[s], msk, 64);
            int   j2 = __shfl_xor(mjj[s], msk, 64);
            if (v2 > mvv[s] || (v2 == mvv[s] && j2 < mjj[s])) { mvv[s]=v2; mjj[s]=j2; }
        }
    if ((lane & 15) == 0) {
        #pragma unroll
        for (int a = 0; a < 4; ++a)
            #pragma unroll
            for (int i = 0; i < 4; ++i) {
                int row = wr*64 + a*16 + (lane>>4)*4 + i;
                gmv[row][wc] = mvv[a*4+i];
                gmi[row][wc] = mjj[a*4+i];
            }
    }
    __syncthreads();
    if (tid < 128) {
        float v = gmv[tid][0]; int j = gmi[tid][0];
        float v1 = gmv[tid][1]; int j1 = gmi[tid][1];
        if (v1 > v || (v1 == v && j1 < j)) { v=v1; j=j1; }
        cval[(size_t)js*NPTS + Mrow + tid] = v;
        cidx[(size_t)js*NPTS + Mrow + tid] = j;
    }
}

__global__ void ccombineK(const float* __restrict__ cval, const int* __restrict__ cidx,
                          const int* __restrict__ counts, int* __restrict__ keep)
{
    int m = blockIdx.x*256 + threadIdx.x;
    float bv = -1.0f; int bj = 1<<30;
    for (int s = 0; s < NSPL; ++s) {
        float v = cval[(size_t)s*NPTS + m]; int j = cidx[(size_t)s*NPTS + m];
        if (v > bv || (v == bv && j < bj)) { bv=v; bj=j; }
    }
    if (counts[m] > 0) atomicOr(&keep[bj], 1);
}

__global__ void keepwriteK(const int* __restrict__ keep, float* __restrict__ out)
{
    int i = blockIdx.x*256 + threadIdx.x;
    out[(size_t)NPTS*DIM + i] = keep[i] ? 1.0f : 0.0f;
}

// ---------------- host ----------------
extern "C" void kernel_launch(void* const* d_in, const int* in_sizes, int n_in,
                              void* d_out, int out_size, void* d_ws, size_t ws_size,
                              hipStream_t stream)
{
    const float* x     = (const float*)d_in[0];
    const float* sigma = (const float*)d_in[1];
    float* out = (float*)d_out;

    const size_t ND4 = (size_t)NPTS * DIM * 4;   // 4 MB
    const size_t NDu = (size_t)NPTS * DIM * 2;   // 2 MB

    struct Cfg { int nch, spl; };
    const Cfg cfgs[] = {{1,4},{2,4},{4,4},{8,4},{8,2},{16,2},{16,1},{32,1}};

    int NCH = 32, SPL = 1;
    size_t o_xh=0,o_xl=0,o_xth=0,o_xtl=0,o_chh=0,o_chl=0,o_c=0,o_cn=0,
           o_cnum=0,o_psum=0,o_wh=0,o_wl=0,o_aval=0,o_aidx=0,o_cval=0,o_cidx=0,
           o_counts=0,o_keep=0,o_done=0,o_shift=0;

    for (int ci = 0; ci < (int)(sizeof(cfgs)/sizeof(cfgs[0])); ++ci) {
        int nch = cfgs[ci].nch, spl = cfgs[ci].spl;
        size_t CHJ = NPTS / nch;
        size_t off = 0;
        auto take = [&](size_t nb) { size_t a = off; off += (nb + 255) & ~(size_t)255; return a; };
        o_xh  = take(NDu);  o_xl  = take(NDu);
        o_xth = take(NDu);  o_xtl = take(NDu);
        o_chh = take(NDu);  o_chl = take(NDu);
        o_c   = take(ND4);  o_cn  = take(ND4);
        o_cnum = take((size_t)spl * ND4);
        o_psum = take((size_t)64 * NPTS * 4);
        o_wh  = take((size_t)NPTS * CHJ * 2);
        o_wl  = take((size_t)NPTS * CHJ * 2);
        o_aval = take((size_t)NSPL*NPTS*4); o_aidx = take((size_t)NSPL*NPTS*4);
        o_cval = take((size_t)NSPL*NPTS*4); o_cidx = take((size_t)NSPL*NPTS*4);
        o_counts = take((size_t)NPTS*4);    o_keep = take((size_t)NPTS*4);
        o_done = take(256); o_shift = take(256);
        NCH = nch; SPL = spl;
        if (off <= ws_size) break;
    }
    const int CHJ  = NPTS / NCH;
    const int JBC  = CHJ / 128;
    const int KLEN = CHJ / SPL;

    char* W = (char*)d_ws;
    U16* xh  = (U16*)(W + o_xh);   U16* xl  = (U16*)(W + o_xl);
    U16* xth = (U16*)(W + o_xth);  U16* xtl = (U16*)(W + o_xtl);
    U16* chh = (U16*)(W + o_chh);  U16* chl = (U16*)(W + o_chl);
    float* c    = (float*)(W + o_c);
    float* cnew = (float*)(W + o_cn);
    float* cnum = (float*)(W + o_cnum);
    float* psum = (float*)(W + o_psum);
    U16* wh = (U16*)(W + o_wh);    U16* wl = (U16*)(W + o_wl);
    float* aval = (float*)(W + o_aval); int* aidx = (int*)(W + o_aidx);
    float* cval = (float*)(W + o_cval); int* cidx = (int*)(W + o_cidx);
    int* counts = (int*)(W + o_counts); int* keep = (int*)(W + o_keep);
    int* done   = (int*)(W + o_done);   int* shiftb = (int*)(W + o_shift);

    initK  <<<dim3(16), dim3(256), 0, stream>>>(counts, keep, done, shiftb);
    normxK <<<dim3(NPTS), dim3(256), 0, stream>>>(x, c, xh, xl);
    transpK<<<dim3(128, 8), dim3(256), 0, stream>>>(x, xth, xtl);

    for (int it = 0; it < MAX_ITERS; ++it) {
        normsplitK<<<dim3(NPTS), dim3(256), 0, stream>>>(c, cnew, chh, chl, done, it > 0);
        for (int ch = 0; ch < NCH; ++ch) {
            simK<<<dim3(JBC, 32), dim3(256), 0, stream>>>(
                chh, chl, xh, xl, wh, wl, psum, done, sigma, ch, CHJ);
            wxK<<<dim3(2, 32, SPL), dim3(256), 0, stream>>>(
                wh, wl, xth, xtl, cnum, done, ch, CHJ, KLEN, ch == 0);
        }
        reduceK<<<dim3(NPTS), dim3(256), 0, stream>>>(psum, cnum, c, cnew, done, shiftb, SPL);
        flagK  <<<dim3(1), dim3(1), 0, stream>>>(done, shiftb);
    }

    finalK    <<<dim3(NPTS), dim3(256), 0, stream>>>(done, c, cnew, out);
    normfinalK<<<dim3(NPTS), dim3(256), 0, stream>>>(out, chh, chl);

    argminMK<<<dim3(NPTS/128, NSPL), dim3(256), 0, stream>>>(xh, xl, chh, chl, aval, aidx);
    acombineK<<<dim3(NPTS/256), dim3(256), 0, stream>>>(aval, aidx, counts);
    ccMK    <<<dim3(NPTS/128, NSPL), dim3(256), 0, stream>>>(chh, chl, counts, sigma, cval, cidx);
    ccombineK<<<dim3(NPTS/256), dim3(256), 0, stream>>>(cval, cidx, counts, keep);
    keepwriteK<<<dim3(NPTS/256), dim3(256), 0, stream>>>(keep, out);
}